// Round 12
// baseline (114.676 us; speedup 1.0000x reference)
//
#include <hip/hip_runtime.h>
#include <hip/hip_bf16.h>

// MEASUREMENT ROUND — kernels byte-identical to R11, wrapped in idempotent
// rep loops (CVT_REPS=4, GEMM_REPS=8, scan x1) so EACH kernel's dispatch
// exceeds the ~40us harness poison-fills and surfaces in rocprof top-5
// with full counters. Outputs unchanged (reps recompute identical values).
//
// Oja scan, reformulated. G[b][n][t] = row_n . x_t for n in [0,1088):
// rows 0..1023 = W0 rows, rows 1024..1087 = X rows (=> S = X X^T).

#define BB 8
#define TT 64
#define NI 1024
#define NO 1024
#define NTOT 1088            // 1024 W rows + 64 X rows
#define NTILES 68            // NTOT/16
#define CVT_REPS 4
#define GEMM_REPS 8

typedef __attribute__((ext_vector_type(8))) short bf16x8;
typedef __attribute__((ext_vector_type(8))) short short8v;
typedef __attribute__((ext_vector_type(4))) float f32x4;

__device__ __forceinline__ short f2bf(float f) {
    __hip_bfloat16 h = __float2bfloat16(f);
    return __builtin_bit_cast(short, h);
}

// ---------- Kernel 0: W (8.39M) and X (0.52M) f32 -> bf16 ----------
__global__ __launch_bounds__(256)
void cvt_kernel(const float* __restrict__ W0, const float* __restrict__ X,
                ushort* __restrict__ Wb16, ushort* __restrict__ Xb16)
{
    const int t = blockIdx.x * 256 + threadIdx.x;   // 0..524287
#pragma unroll 1
    for (int rep = 0; rep < CVT_REPS; ++rep) {
#pragma unroll
        for (int q = 0; q < 2; ++q) {
            const size_t base = ((size_t)q * 524288 + t) * 8;
            const float4 v0 = *reinterpret_cast<const float4*>(W0 + base);
            const float4 v1 = *reinterpret_cast<const float4*>(W0 + base + 4);
            short8v s;
            s[0] = f2bf(v0.x); s[1] = f2bf(v0.y); s[2] = f2bf(v0.z); s[3] = f2bf(v0.w);
            s[4] = f2bf(v1.x); s[5] = f2bf(v1.y); s[6] = f2bf(v1.z); s[7] = f2bf(v1.w);
            *reinterpret_cast<short8v*>(Wb16 + base) = s;
        }
        if (t < 65536) {
            const size_t base = (size_t)t * 8;
            const float4 v0 = *reinterpret_cast<const float4*>(X + base);
            const float4 v1 = *reinterpret_cast<const float4*>(X + base + 4);
            short8v s;
            s[0] = f2bf(v0.x); s[1] = f2bf(v0.y); s[2] = f2bf(v0.z); s[3] = f2bf(v0.w);
            s[4] = f2bf(v1.x); s[5] = f2bf(v1.y); s[6] = f2bf(v1.z); s[7] = f2bf(v1.w);
            *reinterpret_cast<short8v*>(Xb16 + base) = s;
        }
    }
}

// ---------- Kernel 1: G[b][n][t] via MFMA, gload_lds bf16 panel ----------
__global__ __launch_bounds__(256, 4)
void gemm_kernel(const ushort* __restrict__ Wb16, const ushort* __restrict__ Xb16,
                 float* __restrict__ G)
{
    __shared__ __align__(16) ushort As[16 * 1024];   // 32 KB

    const int lane = threadIdx.x & 63;
    const int wave = threadIdx.x >> 6;
    const int b  = blockIdx.x & 7;
    const int nt = blockIdx.x >> 3;
    const int n0 = nt * 16;
    const int t0 = wave * 16;

    const int r  = lane & 15;
    const int kb = lane >> 4;

    const char* __restrict__ panel = (const char*)(
        (n0 < NO) ? (Wb16 + ((size_t)b * NO + n0) * NI)
                  : (Xb16 + ((size_t)b * TT + (n0 - NO)) * NI));

    const int lanebyte = (r << 11) | ((kb ^ (r & 3)) << 4);
    const int rbit = (r >> 2) & 1;
    const char* ApE = (const char*)As + (lanebyte | (rbit << 6));
    const char* ApO = (const char*)As + (lanebyte | ((rbit ^ 1) << 6));

    const ushort* __restrict__ Bbase =
        Xb16 + ((size_t)b * TT + t0 + r) * NI + kb * 8;

    const int tcol = lane & 15;
    const int mrow = (lane >> 4) * 4;

#pragma unroll 1
    for (int rep = 0; rep < GEMM_REPS; ++rep) {
        // ---- stage: 32 issues of 1 KB; linear LDS dest, pre-swizzled src ----
#pragma unroll
        for (int ii = 0; ii < 8; ++ii) {
            const int i   = wave * 8 + ii;
            const int swz = (i >> 1) & 7;
            const char* src = panel + i * 1024 + ((lane ^ swz) << 4);
            char* dst = (char*)As + i * 1024;
            __builtin_amdgcn_global_load_lds(
                (const __attribute__((address_space(1))) void*)src,
                (__attribute__((address_space(3))) void*)dst,
                16, 0, 0);
        }
        __syncthreads();

        f32x4 acc = {0.f, 0.f, 0.f, 0.f};
#pragma unroll 8
        for (int kk2 = 0; kk2 < 16; ++kk2) {
            const bf16x8 ae = *reinterpret_cast<const bf16x8*>(ApE + kk2 * 128);
            const bf16x8 be = *reinterpret_cast<const bf16x8*>(Bbase + kk2 * 64);
            acc = __builtin_amdgcn_mfma_f32_16x16x32_bf16(ae, be, acc, 0, 0, 0);
            const bf16x8 ao = *reinterpret_cast<const bf16x8*>(ApO + kk2 * 128);
            const bf16x8 bo = *reinterpret_cast<const bf16x8*>(Bbase + kk2 * 64 + 32);
            acc = __builtin_amdgcn_mfma_f32_16x16x32_bf16(ao, bo, acc, 0, 0, 0);
        }

#pragma unroll
        for (int rr = 0; rr < 4; ++rr)
            G[((size_t)b * NTOT + n0 + mrow + rr) * TT + t0 + tcol] = acc[rr];

        __syncthreads();   // As safe before next rep's restage
    }
}

// ---------- Kernel 2: lane-parallel projected-Oja scan (R10) ----------
__global__ __launch_bounds__(256, 8)
void scan_kernel(const float* __restrict__ G, float* __restrict__ out)
{
    __shared__ float Sl[TT][TT];
    __shared__ float ybuf[16][68];

    const int tid  = threadIdx.x;
    const int lane = tid & 63;
    const int wave = tid >> 6;
    const int b  = blockIdx.x & 7;
    const int o0 = (blockIdx.x >> 3) * 16;

    {
        const float4* __restrict__ src =
            reinterpret_cast<const float4*>(G + ((size_t)b * NTOT + NO) * TT);
        float4* dst = reinterpret_cast<float4*>(&Sl[0][0]);
#pragma unroll
        for (int q = 0; q < 4; ++q)
            dst[tid + q * 256] = src[tid + q * 256];
    }

    const int r  = lane & 3;
    const int jb = lane >> 2;
    const int row = o0 + wave * 4 + r;

    const float4 uu = *reinterpret_cast<const float4*>(
        G + ((size_t)b * NTOT + row) * TT + jb * 4);
    float u0 = uu.x, u1 = uu.y, u2 = uu.z, u3 = uu.w;

    __syncthreads();

    const float lr   = 1.0f / 1024.0f;
    const float nL2E = -1.44269504f;
    float y0 = 0.f, y1 = 0.f, y2 = 0.f, y3 = 0.f;

#pragma unroll
    for (int t = 0; t < TT; ++t) {
        const int srcl = (t & 0x3C) | r;
        const float uv = ((t & 3) == 0) ? u0 : ((t & 3) == 1) ? u1
                       : ((t & 3) == 2) ? u2 : u3;
        const float pre = __shfl(uv, srcl, 64);

        const float e = __builtin_amdgcn_exp2f(pre * nL2E);
        const float y = __builtin_amdgcn_rcpf(1.0f + e);

        const bool own = (jb == (t >> 2));
        if ((t & 3) == 0) y0 = own ? y : y0;
        if ((t & 3) == 1) y1 = own ? y : y1;
        if ((t & 3) == 2) y2 = own ? y : y2;
        if ((t & 3) == 3) y3 = own ? y : y3;

        const float c2 = lr * y;
        const float c1 = fmaf(-c2, y, 1.0f);

        const float4 s = *reinterpret_cast<const float4*>(&Sl[t][jb * 4]);
        u0 = fmaf(c1, u0, c2 * s.x);
        u1 = fmaf(c1, u1, c2 * s.y);
        u2 = fmaf(c1, u2, c2 * s.z);
        u3 = fmaf(c1, u3, c2 * s.w);
    }

    {
        float4 yv; yv.x = y0; yv.y = y1; yv.z = y2; yv.w = y3;
        *reinterpret_cast<float4*>(&ybuf[wave * 4 + r][jb * 4]) = yv;
    }
    __syncthreads();

    {
        const int t = tid >> 2;
        const int g = tid & 3;
        float4 ov;
        ov.x = ybuf[g * 4 + 0][t];
        ov.y = ybuf[g * 4 + 1][t];
        ov.z = ybuf[g * 4 + 2][t];
        ov.w = ybuf[g * 4 + 3][t];
        *reinterpret_cast<float4*>(
            &out[(size_t)b * TT * NO + (size_t)t * NO + o0 + g * 4]) = ov;
    }
}

extern "C" void kernel_launch(void* const* d_in, const int* in_sizes, int n_in,
                              void* d_out, int out_size, void* d_ws, size_t ws_size,
                              hipStream_t stream) {
    const float* X  = (const float*)d_in[0];   // [8][64][1024]
    const float* W0 = (const float*)d_in[1];   // [8][1024][1024]
    float* out = (float*)d_out;                // [8][64][1024]

    float*  G    = (float*)d_ws;                          // 2,228,224 B
    ushort* Xb16 = (ushort*)((char*)d_ws + 2228224);      // 1,048,576 B
    ushort* Wb16 = (ushort*)((char*)d_ws + 3276800);      // 16,777,216 B

    cvt_kernel<<<2048, 256, 0, stream>>>(W0, X, Wb16, Xb16);
    gemm_kernel<<<BB * NTILES, 256, 0, stream>>>(Wb16, Xb16, G);
    scan_kernel<<<512, 256, 0, stream>>>(G, out);
}

// Round 13
// 30.191 us; speedup vs baseline: 3.7983x; 3.7983x over previous
//
#include <hip/hip_runtime.h>
#include <hip/hip_bf16.h>

// Oja scan, reformulated. G[b][n][t] = row_n . x_t for n in [0,1088):
// rows 0..1023 = W0 rows, rows 1024..1087 = X rows (=> S = X X^T).
// Scan: exact projected Oja recurrence on u[j] = W_t . x_j:
//   y_t = sigmoid(u[t]);  u <- (1-lr*y^2)*u + (lr*y)*S[t,:]
// R13 (from R12 counters: gemm latency-bound, 98% idle, inner-loop global
// B-loads + stage-drain are the serialized round-trips):
//   k0 (xcvt): X -> bf16 (1 MB) only; W-cvt kernel DROPPED (W streams f32).
//   k1 (gemm): 272 blocks x 2 panels. B-tile in 128 VGPRs per wave (loaded
//       once; inner loop has ZERO global loads). A-panel f32 burst-loaded,
//       cvt'd, ds_write'd bf16 with XOR swizzle ((j&7)<<4), double-buffered:
//       panel-1 loads issued BEFORE panel-0 compute (overlap). Inner loop =
//       ds_read_b128 + MFMA only.
//   k2 (scan): unchanged from R10 (lane-parallel, ~4 us).

#define BB 8
#define TT 64
#define NI 1024
#define NO 1024
#define NTOT 1088            // 1024 W rows + 64 X rows
#define NTILES 68            // NTOT/16

typedef __attribute__((ext_vector_type(8))) short bf16x8;
typedef __attribute__((ext_vector_type(4))) float f32x4;

__device__ __forceinline__ short f2bf(float f) {
    __hip_bfloat16 h = __float2bfloat16(f);
    return __builtin_bit_cast(short, h);
}

// ---------- Kernel 0: X (f32, 0.52M elems) -> bf16 ----------
__global__ __launch_bounds__(256)
void xcvt_kernel(const float* __restrict__ X, ushort* __restrict__ Xb16)
{
    const int i = blockIdx.x * 256 + threadIdx.x;   // float4 index, 131072 total
    const float4 v = *reinterpret_cast<const float4*>(X + (size_t)i * 4);
    short4 s;
    s.x = f2bf(v.x); s.y = f2bf(v.y); s.z = f2bf(v.z); s.w = f2bf(v.w);
    *reinterpret_cast<short4*>(Xb16 + (size_t)i * 4) = s;
}

// ---------- Kernel 1: G[b][n][t] via MFMA ----------
// Grid 272 = 34 slots x 8 batches (b = blockIdx&7). Block: 256 thr, 4 waves;
// wave w owns t-tile w for BOTH panels nt = slot*2, slot*2+1.
__global__ __launch_bounds__(256, 1)
void gemm_kernel(const float* __restrict__ X, const float* __restrict__ W0,
                 const ushort* __restrict__ Xb16, float* __restrict__ G)
{
    __shared__ __align__(16) ushort As[2][16 * 1024];   // 2 x 32 KB bf16

    const int tid  = threadIdx.x;
    const int lane = tid & 63;
    const int wave = tid >> 6;
    const int b    = blockIdx.x & 7;
    const int slot = blockIdx.x >> 3;    // 0..33
    const int nt0  = slot * 2;
    const int t0   = wave * 16;

    const int r  = lane & 15;            // fragment row
    const int kb = lane >> 4;            // k-block 0..3

    // ---- B-tile -> registers (once; inner loop has no global loads) ----
    // breg[kk] = Xb16[b][t0+r][kb*8 + kk*32 .. +8]
    bf16x8 breg[32];
    {
        const ushort* __restrict__ Bbase =
            Xb16 + ((size_t)b * TT + t0 + r) * NI + kb * 8;
#pragma unroll
        for (int kk = 0; kk < 32; ++kk)
            breg[kk] = *reinterpret_cast<const bf16x8*>(Bbase + kk * 32);
    }

    // ---- stage mapping: thread (j = tid>>4 row, x = tid&15), 16 chunks ----
    const int j  = tid >> 4;
    const int x  = tid & 15;
    const int sj = (j & 7) << 4;         // XOR swizzle for row j

    // A source row for panel nt (W rows, or X rows for the Gram part)
    const float* __restrict__ Xb = X + (size_t)b * TT * NI;
    const float* __restrict__ Wb = W0 + (size_t)b * NO * NI;
#define SRCROW(nt) ((((nt) * 16) < NO) ? (Wb + ((size_t)((nt) * 16) + j) * NI) \
                                       : (Xb + ((size_t)((nt) * 16 - NO) + j) * NI))

    float4 v[16];
    // prologue: load panel 0 (16 x float4/thread, one burst)
    {
        const float* sr = SRCROW(nt0) + x * 4;
#pragma unroll
        for (int c = 0; c < 16; ++c)
            v[c] = *reinterpret_cast<const float4*>(sr + c * 64);
    }
    // cvt + swizzled ds_write -> buf 0
#pragma unroll
    for (int c = 0; c < 16; ++c) {
        short4 s4;
        s4.x = f2bf(v[c].x); s4.y = f2bf(v[c].y);
        s4.z = f2bf(v[c].z); s4.w = f2bf(v[c].w);
        char* dst = (char*)As[0] + j * 2048 + c * 128 + ((x * 8) ^ sj);
        *reinterpret_cast<short4*>(dst) = s4;
    }
    __syncthreads();

    // swizzled read bases (verified: phys = r*2048 + ((kb^(r&3))<<4)
    //  | (((kk&1)^((r>>2)&1))<<6) + (kk>>1)*128 )
    const int lanebyte = (r << 11) | ((kb ^ (r & 3)) << 4);
    const int rbit = (r >> 2) & 1;

    const int tcol = lane & 15;
    const int mrow = (lane >> 4) * 4;

#pragma unroll
    for (int p = 0; p < 2; ++p) {
        if (p == 0) {
            // issue panel-1 loads now; they fly during panel-0 compute
            const float* sr = SRCROW(nt0 + 1) + x * 4;
#pragma unroll
            for (int c = 0; c < 16; ++c)
                v[c] = *reinterpret_cast<const float4*>(sr + c * 64);
        }

        const char* base = (const char*)As[p] + lanebyte;
        const char* ApE = base + (rbit << 6);
        const char* ApO = base + ((rbit ^ 1) << 6);

        f32x4 acc = {0.f, 0.f, 0.f, 0.f};
#pragma unroll
        for (int kk2 = 0; kk2 < 16; ++kk2) {
            const bf16x8 ae = *reinterpret_cast<const bf16x8*>(ApE + kk2 * 128);
            acc = __builtin_amdgcn_mfma_f32_16x16x32_bf16(ae, breg[2 * kk2], acc, 0, 0, 0);
            const bf16x8 ao = *reinterpret_cast<const bf16x8*>(ApO + kk2 * 128);
            acc = __builtin_amdgcn_mfma_f32_16x16x32_bf16(ao, breg[2 * kk2 + 1], acc, 0, 0, 0);
        }

        // D layout: col t = lane&15, row n = (lane>>4)*4 + rr  [m89-verified]
        const int n0 = (nt0 + p) * 16;
#pragma unroll
        for (int rr = 0; rr < 4; ++rr)
            G[((size_t)b * NTOT + n0 + mrow + rr) * TT + t0 + tcol] = acc[rr];

        if (p == 0) {
            // write-late: cvt + ds_write panel 1 into buf 1, then barrier
#pragma unroll
            for (int c = 0; c < 16; ++c) {
                short4 s4;
                s4.x = f2bf(v[c].x); s4.y = f2bf(v[c].y);
                s4.z = f2bf(v[c].z); s4.w = f2bf(v[c].w);
                char* dst = (char*)As[1] + j * 2048 + c * 128 + ((x * 8) ^ sj);
                *reinterpret_cast<short4*>(dst) = s4;
            }
            __syncthreads();
        }
    }
#undef SRCROW
}

// ---------- Kernel 2: lane-parallel projected-Oja scan (R10) ----------
__global__ __launch_bounds__(256, 8)
void scan_kernel(const float* __restrict__ G, float* __restrict__ out)
{
    __shared__ float Sl[TT][TT];
    __shared__ float ybuf[16][68];

    const int tid  = threadIdx.x;
    const int lane = tid & 63;
    const int wave = tid >> 6;
    const int b  = blockIdx.x & 7;
    const int o0 = (blockIdx.x >> 3) * 16;

    {
        const float4* __restrict__ src =
            reinterpret_cast<const float4*>(G + ((size_t)b * NTOT + NO) * TT);
        float4* dst = reinterpret_cast<float4*>(&Sl[0][0]);
#pragma unroll
        for (int q = 0; q < 4; ++q)
            dst[tid + q * 256] = src[tid + q * 256];
    }

    const int r  = lane & 3;
    const int jb = lane >> 2;
    const int row = o0 + wave * 4 + r;

    const float4 uu = *reinterpret_cast<const float4*>(
        G + ((size_t)b * NTOT + row) * TT + jb * 4);
    float u0 = uu.x, u1 = uu.y, u2 = uu.z, u3 = uu.w;

    __syncthreads();

    const float lr   = 1.0f / 1024.0f;
    const float nL2E = -1.44269504f;
    float y0 = 0.f, y1 = 0.f, y2 = 0.f, y3 = 0.f;

#pragma unroll
    for (int t = 0; t < TT; ++t) {
        const int srcl = (t & 0x3C) | r;
        const float uv = ((t & 3) == 0) ? u0 : ((t & 3) == 1) ? u1
                       : ((t & 3) == 2) ? u2 : u3;
        const float pre = __shfl(uv, srcl, 64);

        const float e = __builtin_amdgcn_exp2f(pre * nL2E);
        const float y = __builtin_amdgcn_rcpf(1.0f + e);

        const bool own = (jb == (t >> 2));
        if ((t & 3) == 0) y0 = own ? y : y0;
        if ((t & 3) == 1) y1 = own ? y : y1;
        if ((t & 3) == 2) y2 = own ? y : y2;
        if ((t & 3) == 3) y3 = own ? y : y3;

        const float c2 = lr * y;
        const float c1 = fmaf(-c2, y, 1.0f);

        const float4 s = *reinterpret_cast<const float4*>(&Sl[t][jb * 4]);
        u0 = fmaf(c1, u0, c2 * s.x);
        u1 = fmaf(c1, u1, c2 * s.y);
        u2 = fmaf(c1, u2, c2 * s.z);
        u3 = fmaf(c1, u3, c2 * s.w);
    }

    {
        float4 yv; yv.x = y0; yv.y = y1; yv.z = y2; yv.w = y3;
        *reinterpret_cast<float4*>(&ybuf[wave * 4 + r][jb * 4]) = yv;
    }
    __syncthreads();

    {
        const int t = tid >> 2;
        const int g = tid & 3;
        float4 ov;
        ov.x = ybuf[g * 4 + 0][t];
        ov.y = ybuf[g * 4 + 1][t];
        ov.z = ybuf[g * 4 + 2][t];
        ov.w = ybuf[g * 4 + 3][t];
        *reinterpret_cast<float4*>(
            &out[(size_t)b * TT * NO + (size_t)t * NO + o0 + g * 4]) = ov;
    }
}

extern "C" void kernel_launch(void* const* d_in, const int* in_sizes, int n_in,
                              void* d_out, int out_size, void* d_ws, size_t ws_size,
                              hipStream_t stream) {
    const float* X  = (const float*)d_in[0];   // [8][64][1024]
    const float* W0 = (const float*)d_in[1];   // [8][1024][1024]
    float* out = (float*)d_out;                // [8][64][1024]

    float*  G    = (float*)d_ws;                          // 2,228,224 B
    ushort* Xb16 = (ushort*)((char*)d_ws + 2228224);      // 1,048,576 B

    xcvt_kernel<<<512, 256, 0, stream>>>(X, Xb16);
    gemm_kernel<<<34 * BB, 256, 0, stream>>>(X, W0, Xb16, G);
    scan_kernel<<<512, 256, 0, stream>>>(G, out);
}